// Round 10
// baseline (137.502 us; speedup 1.0000x reference)
//
#include <hip/hip_runtime.h>

typedef __bf16 bf16;
typedef __bf16 bf16x4 __attribute__((ext_vector_type(4)));
typedef __bf16 bf16x8 __attribute__((ext_vector_type(8)));
typedef float  f32x4  __attribute__((ext_vector_type(4)));
typedef float  f32x16 __attribute__((ext_vector_type(16)));

#define T_DIM 256
#define B_DIM 256
#define NIN   512
#define NH    512
#define NEMB  256
#define NX    768      // NIN + NEMB
#define NG    1536     // 3*NH
#define MTOT  65536    // T*B

__device__ __forceinline__ float fast_tanh(float x) {
    float e = __expf(2.0f * x);
    return 1.0f - 2.0f * __builtin_amdgcn_rcpf(e + 1.0f);
}
__device__ __forceinline__ float fast_sigmoid(float x) {
    return __builtin_amdgcn_rcpf(1.0f + __expf(-x));
}

// ---------------- weight/h conversion; w_i2h -> frag-major Wfrag ----------------
// Wfrag[(g*32+ks)*64 + lane]*8 + j  =  w_i2h[g*32+(lane&31)][ks*16+(lane>>5)*8+j]
// so a wave's b-frag load for (colgroup g, kstep ks) is one coalesced 1KB chunk.
__global__ __launch_bounds__(256) void cvt_weights(
    const float* __restrict__ a0, const float* __restrict__ a1,
    const float* __restrict__ a2, const float* __restrict__ a3,
    const float* __restrict__ a4,
    bf16* __restrict__ b0, bf16* __restrict__ b1, bf16* __restrict__ b2,
    bf16* __restrict__ b3, bf16* __restrict__ b4) {
    const int N0 = 65536, N1 = 131072, N2 = 425984, N3 = 622592, N4 = 655360;
    for (int i = blockIdx.x * 256 + threadIdx.x; i < N4; i += gridDim.x * 256) {
        const float* s; bf16* d; int j; bool img = false;
        if (i < N0)      { s = a0; d = b0; j = i; img = true; }
        else if (i < N1) { s = a1; d = b1; j = i - N0; }
        else if (i < N2) { s = a2; d = b2; j = i - N1; }
        else if (i < N3) { s = a3; d = b3; j = i - N2; }
        else             { s = a4; d = b4; j = i - N3; }
        float4 v = reinterpret_cast<const float4*>(s)[j];
        bf16x4 o = { (bf16)v.x, (bf16)v.y, (bf16)v.z, (bf16)v.w };
        if (img) {
            int e = j * 4, col = e >> 9, K = e & 511;
            int g = col >> 5, cl = col & 31;
            int ks = K >> 4, kh = (K >> 3) & 1, j0 = K & 7;   // j0 in {0,4}
            int lane = kh * 32 + cl;
            int off = (((g * 32 + ks) * 64) + lane) * 8 + j0;
            *reinterpret_cast<bf16x4*>(d + off) = o;
        } else {
            reinterpret_cast<bf16x4*>(d)[j] = o;
        }
    }
}

// ---------------- generic GEMM: C[M,N] = A[M,K] * B[N,K]^T + bias[N] ----------------
__global__ __launch_bounds__(256) void gemm_bias(
    const bf16* __restrict__ A, const bf16* __restrict__ B,
    const float* __restrict__ bias, float* __restrict__ C,
    int M, int N, int K) {
    __shared__ bf16 At[64][40];
    __shared__ bf16 Bt[64][40];
    const int tid = threadIdx.x;
    const int m0 = blockIdx.y * 64, n0 = blockIdx.x * 64;
    const int wid = tid >> 6, lane = tid & 63, hi = lane >> 4, lo = lane & 15;
    const int srow = tid >> 2, sseg = tid & 3;
    f32x4 acc[4] = {};

    for (int kk = 0; kk < K; kk += 32) {
        bf16x8 av = *reinterpret_cast<const bf16x8*>(A + (size_t)(m0 + srow) * K + kk + sseg * 8);
        bf16x8 bv = *reinterpret_cast<const bf16x8*>(B + (size_t)(n0 + srow) * K + kk + sseg * 8);
        __syncthreads();
        *reinterpret_cast<bf16x8*>(&At[srow][sseg * 8]) = av;
        *reinterpret_cast<bf16x8*>(&Bt[srow][sseg * 8]) = bv;
        __syncthreads();
        bf16x8 a = *reinterpret_cast<const bf16x8*>(&At[wid * 16 + lo][hi * 8]);
#pragma unroll
        for (int nt = 0; nt < 4; ++nt) {
            bf16x8 b = *reinterpret_cast<const bf16x8*>(&Bt[nt * 16 + lo][hi * 8]);
            acc[nt] = __builtin_amdgcn_mfma_f32_16x16x32_bf16(a, b, acc[nt], 0, 0, 0);
        }
    }
#pragma unroll
    for (int nt = 0; nt < 4; ++nt) {
        int n = n0 + nt * 16 + lo;
        float bv = bias[n];
#pragma unroll
        for (int r = 0; r < 4; ++r) {
            int m = m0 + wid * 16 + hi * 4 + r;
            C[(size_t)m * N + n] = acc[nt][r] + bv;
        }
    }
}

// ---------------- fused emit kernel (v9: B persistent in registers, stream A) ----------
// emit[m] = sum_n tanh((feats W^T)[m,n] + h_[b(m),n]) * w_score[n]
// Grid: 2 n-slabs x 128 m-blocks (512 rows). Block: 8 waves; wave owns 32 cols,
// holding its whole B panel (32 frags, 128 VGPR) for all K. Zero B traffic in loop.
// A: 32-row tiles streamed f32->bf16 through a 2x33KB LDS dbuf; one barrier/tile.
// MFMA: 32x32x16, two independent even/odd-k accumulator chains.
__global__ __launch_bounds__(512, 2) void emit_kernel(
    const float* __restrict__ feats, const bf16* __restrict__ Wfrag,
    const float* __restrict__ hbuf, const float* __restrict__ wscore,
    float* __restrict__ emit_part) {
    __shared__ bf16 Alds[2][32][516];   // pad +4: row stride 1032B, 2-way-free b64 reads
    __shared__ float ew[2][8][32];
    const int tid = threadIdx.x;
    const int wid = tid >> 6, lane = tid & 63;
    const int half = lane >> 5, l31 = lane & 31;
    const int slab = blockIdx.x & 1, mb = blockIdx.x >> 1;
    const int m0 = mb * 512;
    const int col = slab * 256 + wid * 32 + l31;

    // ---- B prologue: 32 coalesced 1KB frag loads -> 128 VGPR, persistent ----
    const bf16* wsrc = Wfrag + (size_t)((slab * 8 + wid) * 32) * 512 + lane * 8;
    bf16x8 bfr[32];
#pragma unroll
    for (int ks = 0; ks < 32; ++ks)
        bfr[ks] = *reinterpret_cast<const bf16x8*>(wsrc + ks * 512);

    // ---- A staging map: chunk c = tid + j*512; row = c>>7, f4 = c&127 ----
    const float* asrc = feats + (size_t)m0 * NIN + tid * 4;
    const int awrow = tid >> 7, awcol = (tid & 127) * 4;

    float4 st[8];
#pragma unroll
    for (int j = 0; j < 8; ++j)
        st[j] = *reinterpret_cast<const float4*>(asrc + j * 2048);
#pragma unroll
    for (int j = 0; j < 8; ++j) {
        bf16x4 o = { (bf16)st[j].x, (bf16)st[j].y, (bf16)st[j].z, (bf16)st[j].w };
        *reinterpret_cast<bf16x4*>(&Alds[0][awrow + 4 * j][awcol]) = o;
    }
    __syncthreads();

    const float wsl = wscore[col];

    for (int it = 0; it < 16; ++it) {
        const int cur = it & 1;
        // issue A(it+1) loads; covered by this tile's ~3k-cycle compute window
        if (it < 15) {
            const float* an = asrc + (size_t)(it + 1) * 32 * NIN;
#pragma unroll
            for (int j = 0; j < 8; ++j)
                st[j] = *reinterpret_cast<const float4*>(an + j * 2048);
        }

        // ---- K-loop: 32 MFMA, a-frags from LDS, b-frags from registers ----
        f32x16 acc0 = {}, acc1 = {};
#pragma unroll
        for (int ks = 0; ks < 32; ks += 2) {
            const bf16* ap0 = &Alds[cur][l31][ks * 16 + half * 8];
            bf16x4 p0 = *reinterpret_cast<const bf16x4*>(ap0);
            bf16x4 p1 = *reinterpret_cast<const bf16x4*>(ap0 + 4);
            bf16x8 a0 = { p0[0], p0[1], p0[2], p0[3], p1[0], p1[1], p1[2], p1[3] };
            acc0 = __builtin_amdgcn_mfma_f32_32x32x16_bf16(a0, bfr[ks], acc0, 0, 0, 0);
            const bf16* ap1 = &Alds[cur][l31][(ks + 1) * 16 + half * 8];
            bf16x4 q0 = *reinterpret_cast<const bf16x4*>(ap1);
            bf16x4 q1 = *reinterpret_cast<const bf16x4*>(ap1 + 4);
            bf16x8 a1 = { q0[0], q0[1], q0[2], q0[3], q1[0], q1[1], q1[2], q1[3] };
            acc1 = __builtin_amdgcn_mfma_f32_32x32x16_bf16(a1, bfr[ks + 1], acc1, 0, 0, 0);
        }

        // ---- epilogue: tanh + dot(w_score) + col-reduce for this 32-row tile ----
        float e[16];
#pragma unroll
        for (int r = 0; r < 16; ++r) {
            int row = (r & 3) + 8 * (r >> 2) + 4 * half;      // verified 32x32 C map
            int brow = (it * 32 + row) & (B_DIM - 1);
            float x = acc0[r] + acc1[r] + hbuf[(size_t)brow * NH + col];
            e[r] = fast_tanh(x) * wsl;
        }
#pragma unroll
        for (int r = 0; r < 16; ++r)
#pragma unroll
            for (int off = 1; off < 32; off <<= 1)
                e[r] += __shfl_xor(e[r], off, 64);
        if (l31 == 0) {
#pragma unroll
            for (int r = 0; r < 16; ++r)
                ew[cur][wid][(r & 3) + 8 * (r >> 2) + 4 * half] = e[r];
        }

        // ---- stage A(it+1) into the other buffer ----
        if (it < 15) {
#pragma unroll
            for (int j = 0; j < 8; ++j) {
                bf16x4 o = { (bf16)st[j].x, (bf16)st[j].y, (bf16)st[j].z, (bf16)st[j].w };
                *reinterpret_cast<bf16x4*>(&Alds[cur ^ 1][awrow + 4 * j][awcol]) = o;
            }
        }
        __syncthreads();
        // ew[cur] is stable until iter it+2's tail; safe to reduce now
        if (tid < 32) {
            float s = 0.0f;
#pragma unroll
            for (int w = 0; w < 8; ++w) s += ew[cur][w][tid];
            emit_part[(size_t)slab * MTOT + m0 + it * 32 + tid] = s;
        }
    }
}

// ---------------- softmax over T (per column b), summing 2 slab partials ----------------
__global__ __launch_bounds__(256) void softmax_t(
    const float* __restrict__ emit_part, float* __restrict__ alpha,
    float* __restrict__ out_alpha) {
    int b = blockIdx.x, t = threadIdx.x;
    int wv = t >> 6, ln = t & 63;
    size_t m = (size_t)t * B_DIM + b;
    float e = emit_part[m] + emit_part[MTOT + m];
    float mx = e;
#pragma unroll
    for (int off = 32; off; off >>= 1) mx = fmaxf(mx, __shfl_xor(mx, off, 64));
    __shared__ float red[4], red2[4];
    if (ln == 0) red[wv] = mx;
    __syncthreads();
    mx = fmaxf(fmaxf(red[0], red[1]), fmaxf(red[2], red[3]));
    float p = __expf(e - mx);
    float s = p;
#pragma unroll
    for (int off = 32; off; off >>= 1) s += __shfl_xor(s, off, 64);
    if (ln == 0) red2[wv] = s;
    __syncthreads();
    float inv = __builtin_amdgcn_rcpf(red2[0] + red2[1] + red2[2] + red2[3]);
    float a = p * inv;
    alpha[m] = a;
    out_alpha[m] = a;
}

// ---------------- context + build_x fused (reads f32 feats, L3-resident) ----------------
__global__ __launch_bounds__(256) void ctx_kernel(
    const float* __restrict__ feats, const float* __restrict__ alpha,
    const float* __restrict__ emb, bf16* __restrict__ x) {
    int b = blockIdx.x;
    __shared__ float al[T_DIM];
    __shared__ float red[4][512];
    int tid = threadIdx.x;
    al[tid] = alpha[(size_t)tid * B_DIM + b];
    __syncthreads();
    int c8 = tid & 63, tq = tid >> 6;
    float acc[8] = {};
#pragma unroll 4
    for (int t = tq * 64; t < tq * 64 + 64; ++t) {
        const float* src = feats + ((size_t)(t * B_DIM + b)) * NIN + c8 * 8;
        float4 v0 = *reinterpret_cast<const float4*>(src);
        float4 v1 = *reinterpret_cast<const float4*>(src + 4);
        float a = al[t];
        acc[0] += a * v0.x; acc[1] += a * v0.y; acc[2] += a * v0.z; acc[3] += a * v0.w;
        acc[4] += a * v1.x; acc[5] += a * v1.y; acc[6] += a * v1.z; acc[7] += a * v1.w;
    }
#pragma unroll
    for (int j = 0; j < 8; ++j) red[tq][c8 * 8 + j] = acc[j];
    __syncthreads();
#pragma unroll
    for (int k = 0; k < 2; ++k) {
        int c = tid * 2 + k;
        float s = red[0][c] + red[1][c] + red[2][c] + red[3][c];
        x[(size_t)b * NX + c] = (bf16)s;
    }
    x[(size_t)b * NX + NIN + tid] = (bf16)emb[(size_t)b * NEMB + tid];
}

// ---------------- GRU gates ----------------
__global__ __launch_bounds__(256) void gru_kernel(
    const float* __restrict__ gi, const float* __restrict__ gh,
    const float* __restrict__ h, float* __restrict__ out) {
    int idx = blockIdx.x * 256 + threadIdx.x;
    int b = idx >> 9, j = idx & 511;
    const float* gib = gi + (size_t)b * NG;
    const float* ghb = gh + (size_t)b * NG;
    float r = fast_sigmoid(gib[j] + ghb[j]);
    float z = fast_sigmoid(gib[NH + j] + ghb[NH + j]);
    float n = fast_tanh(gib[2 * NH + j] + r * ghb[2 * NH + j]);
    out[idx] = (1.0f - z) * n + z * h[idx];
}

extern "C" void kernel_launch(void* const* d_in, const int* in_sizes, int n_in,
                              void* d_out, int out_size, void* d_ws, size_t ws_size,
                              hipStream_t stream) {
    const float* feats = (const float*)d_in[0];
    const float* h     = (const float*)d_in[1];
    const float* emb   = (const float*)d_in[2];
    const float* w_i2h = (const float*)d_in[3];
    const float* w_h2h = (const float*)d_in[4];
    const float* b_h2h = (const float*)d_in[5];
    const float* w_sc  = (const float*)d_in[6];
    const float* w_ih  = (const float*)d_in[7];
    const float* w_hh  = (const float*)d_in[8];
    const float* b_ih  = (const float*)d_in[9];
    const float* b_hh  = (const float*)d_in[10];
    float* out = (float*)d_out;

    char* ws = (char*)d_ws;
    bf16*  Wfrag   = (bf16*)(ws);                 // 524288 (frag-major image)
    bf16*  w_h2h_b = (bf16*)(ws + 524288);        // 524288
    bf16*  w_ih_b  = (bf16*)(ws + 1048576);       // 2359296
    bf16*  w_hh_b  = (bf16*)(ws + 3407872);       // 1572864
    bf16*  h_b     = (bf16*)(ws + 4980736);       // 262144
    bf16*  x_b     = (bf16*)(ws + 5242880);       // 393216
    float* hbuf    = (float*)(ws + 5636096);      // 524288
    float* emit_p  = (float*)(ws + 6160384);      // 524288 (2 slab partials)
    float* alpha   = (float*)(ws + 6684672);      // 262144
    float* gi      = (float*)(ws + 6946816);      // 1572864
    float* gh      = (float*)(ws + 8519680);      // 1572864  -> total 10092544

    // 1) weight/h conversions (w_i2h -> frag-major Wfrag)
    cvt_weights<<<1024, 256, 0, stream>>>(w_i2h, w_h2h, w_ih, w_hh, h,
                                          Wfrag, w_h2h_b, w_ih_b, w_hh_b, h_b);

    // 2) h_ = h @ w_h2h^T + b_h2h ; gh = h @ w_hh^T + b_hh
    gemm_bias<<<dim3(8, 4), 256, 0, stream>>>(h_b, w_h2h_b, b_h2h, hbuf, 256, NH, NH);
    gemm_bias<<<dim3(24, 4), 256, 0, stream>>>(h_b, w_hh_b, b_hh, gh, 256, NG, NH);

    // 3) fused emit (B-in-registers structure)
    emit_kernel<<<256, 512, 0, stream>>>(feats, Wfrag, hbuf, w_sc, emit_p);

    // 4) alpha = softmax_T(sum of 2 partials); also output 1
    softmax_t<<<256, 256, 0, stream>>>(emit_p, alpha, out + 131072);

    // 5) context + x build (fused, f32 feats from L3)
    ctx_kernel<<<256, 256, 0, stream>>>(feats, alpha, emb, x_b);

    // 6) gi = x @ w_ih^T + b_ih
    gemm_bias<<<dim3(24, 4), 256, 0, stream>>>(x_b, w_ih_b, b_ih, gi, 256, NG, NX);

    // 7) GRU -> nh (output 0)
    gru_kernel<<<512, 256, 0, stream>>>(gi, gh, h, out);
}